// Round 10
// baseline (75.707 us; speedup 1.0000x reference)
//
#include <hip/hip_runtime.h>
#include <hip/hip_bf16.h>

#define DDIM   256   // K (feature dim)
#define BROWS  256   // block output rows (4 waves x 64 rows)
#define BCOLS   32   // B tile columns
#define NTILES   8   // B tiles per block -> 256 cols per chunk

typedef float f32x4 __attribute__((ext_vector_type(4)));

// pack 4 f32 -> 4 fp8 e4m3 bytes
__device__ __forceinline__ unsigned int pack4_fp8(float a0, float a1, float a2, float a3) {
  int v = __builtin_amdgcn_cvt_pk_fp8_f32(a0, a1, 0, false);   // bytes 0,1
  v = __builtin_amdgcn_cvt_pk_fp8_f32(a2, a3, v, true);        // bytes 2,3
  return (unsigned int)v;
}

// ---- prep: one wave per row; writes UNIT-NORM fp8 rows + exact f32 diag ----
__global__ __launch_bounds__(256) void prep_kernel(
    const float* __restrict__ q, const float* __restrict__ r,
    unsigned char* __restrict__ qf8, unsigned char* __restrict__ rf8,
    float* __restrict__ pos, float* __restrict__ row_sum) {
  int lane = threadIdx.x & 63, wave = threadIdx.x >> 6;
  int row = blockIdx.x * 4 + wave;
  size_t base = (size_t)row * DDIM + lane * 4;
  float4 qv = *(const float4*)(q + base);
  float4 rv = *(const float4*)(r + base);
  float qq = qv.x*qv.x + qv.y*qv.y + qv.z*qv.z + qv.w*qv.w;
  float rr = rv.x*rv.x + rv.y*rv.y + rv.z*rv.z + rv.w*rv.w;
  float qr = qv.x*rv.x + qv.y*rv.y + qv.z*rv.z + qv.w*rv.w;
  #pragma unroll
  for (int m = 1; m < 64; m <<= 1) {
    qq += __shfl_xor(qq, m);
    rr += __shfl_xor(rr, m);
    qr += __shfl_xor(qr, m);
  }
  float iq = 1.0f / sqrtf(qq);
  float ir = 1.0f / sqrtf(rr);
  unsigned int qp = pack4_fp8(qv.x*iq, qv.y*iq, qv.z*iq, qv.w*iq);
  unsigned int rp = pack4_fp8(rv.x*ir, rv.y*ir, rv.z*ir, rv.w*ir);
  *(unsigned int*)(qf8 + base) = qp;
  *(unsigned int*)(rf8 + base) = rp;
  if (lane == 0) {
    pos[row] = qr * iq * ir;   // exact f32 diagonal from raw inputs
    row_sum[row] = 0.0f;
  }
}

// stage one 32-col x 256-K fp8 B tile (8 KB) into LDS, async.
// LDS layout: byte(col, koff) = col*256 + (koff ^ ((col&15)<<4)).
// global_load_lds writes linearly (uniform base + lane*16), so the SOURCE is
// inverse-swizzled (rule 21). 256 threads x 2 iters x 16B = 8 KB.
__device__ __forceinline__ void stage_tile(unsigned char* dst,
                                           const unsigned char* src_base,
                                           int col0, int wid, int lane) {
  const char* gb = (const char*)src_base + (size_t)col0 * 256;
  #pragma unroll
  for (int it = 0; it < 2; ++it) {
    int cb = it * 256 + wid * 64;        // wave-uniform chunk base (16B units)
    int ch = cb + lane;                  // 0..511
    int cc = ch >> 4;                    // tile-local col 0..31
    int w  = (ch & 15) << 4;             // 16B block within the 256B row
    int src = cc * 256 + (w ^ ((cc & 15) << 4));
    __builtin_amdgcn_global_load_lds(
        (const __attribute__((address_space(1))) void*)(gb + src),
        (__attribute__((address_space(3))) void*)(dst + cb * 16),
        16, 0, 0);
  }
}

// one 256x32 tile: wave = 64 rows x 32 cols. A (fp8) resident in registers
// (4 frags x 8 K-slices = 64 VGPR), B from LDS b64. Per K-step:
// 2 ds_read_b64 -> 8 MFMA (3.2:1 MFMA:LDS at CU level).
__device__ __forceinline__ void compute_tile(
    const unsigned char* Bt, const long (&av)[4][8], float (&rs)[16],
    int g, int c) {
  // cols c and c+16 share swz = c<<4 (since (c+16)&15 == c); col c+16 is a
  // flat +4096B offset (imm-foldable into the second ds_read).
  const char* Bb = (const char*)Bt + (size_t)c * 256;
  f32x4 acc[4][2];
  const f32x4 zero = {0.f, 0.f, 0.f, 0.f};
  #pragma unroll
  for (int m = 0; m < 4; ++m) { acc[m][0] = zero; acc[m][1] = zero; }

  #pragma unroll
  for (int ks = 0; ks < 8; ++ks) {
    int koff = (ks * 32 + g * 8) ^ (c << 4);
    long bv0 = *(const long*)(Bb + koff);
    long bv1 = *(const long*)(Bb + 4096 + koff);
    #pragma unroll
    for (int m = 0; m < 4; ++m) {
      acc[m][0] = __builtin_amdgcn_mfma_f32_16x16x32_fp8_fp8(av[m][ks], bv0, acc[m][0], 0, 0, 0);
      acc[m][1] = __builtin_amdgcn_mfma_f32_16x16x32_fp8_fp8(av[m][ks], bv1, acc[m][1], 0, 0, 0);
    }
  }

  // unit-norm inputs: score = acc. C layout: col = half*16+c, row = m*16+g*4+jj
  #pragma unroll
  for (int m = 0; m < 4; ++m)
    #pragma unroll
    for (int jj = 0; jj < 4; ++jj)
      rs[m * 4 + jj] += __expf(acc[m][0][jj]) + __expf(acc[m][1][jj]);
}

// 256 threads = 4 waves x 64 rows. Per-wave total register demand:
// av(64) + acc(32) + rs(16) + transients(~14) ~ 126 <= 128, so
// launch_bounds(256,4) (4 waves/EU = 128-reg budget = 4 blocks/CU) fits with
// NO spill and NO AGPR overflow — R9's failure was total regs 152 (88 VGPR +
// 64 AGPR) -> 3 waves/SIMD -> only ONE 8-wave block resident per CU.
// 4 small blocks/CU give 4 independent barrier groups: one block's stage and
// barrier drain hide under the other blocks' MFMA phases.
__global__ __launch_bounds__(256, 4) void gemm_lse_kernel(
    const unsigned char* __restrict__ qf8, const unsigned char* __restrict__ rf8,
    float* __restrict__ row_sum) {
  __shared__ __attribute__((aligned(16))) unsigned char Bl[2][BCOLS * DDIM]; // 2 x 8 KB

  const int tid  = threadIdx.x;
  const int lane = tid & 63;
  const int wid  = tid >> 6;            // 4 waves, each owns 64 rows
  const int g = lane >> 4, c = lane & 15;
  const int row0  = blockIdx.x * BROWS;
  const int col00 = blockIdx.y * (NTILES * BCOLS);

  // issue stage of tile 0 first; latency hides under the A-register loads
  stage_tile(&Bl[0][0], rf8, col00, wid, lane);

  // A fragments -> registers (4 row-frags x 8 K-slices = 64 VGPR), read once
  long av[4][8];
  const char* Ab = (const char*)qf8;
  #pragma unroll
  for (int m = 0; m < 4; ++m) {
    size_t rb = (size_t)(row0 + wid * 64 + m * 16 + c) * 256;
    #pragma unroll
    for (int ks = 0; ks < 8; ++ks)
      av[m][ks] = *(const long*)(Ab + rb + ks * 32 + g * 8);
  }

  float rs[16];
  #pragma unroll
  for (int k = 0; k < 16; ++k) rs[k] = 0.0f;

  __syncthreads();   // tile 0 resident

  // 2-phase pipeline: issue stage(t+1) BEFORE compute(t); the single
  // __syncthreads per tile drains vmcnt AFTER compute so in-flight loads
  // hide under MFMA. Manual x2 unroll keeps buffer indices compile-time.
  for (int t = 0; t < NTILES; t += 2) {
    if (t + 1 < NTILES)
      stage_tile(&Bl[1][0], rf8, col00 + (t + 1) * BCOLS, wid, lane);
    compute_tile(&Bl[0][0], av, rs, g, c);
    __syncthreads();

    if (t + 2 < NTILES)
      stage_tile(&Bl[0][0], rf8, col00 + (t + 2) * BCOLS, wid, lane);
    compute_tile(&Bl[1][0], av, rs, g, c);
    __syncthreads();
  }

  // reduce the 16 column-lanes holding the same row, one atomic per row
  #pragma unroll
  for (int k = 0; k < 16; ++k) {
    float v = rs[k];
    v += __shfl_xor(v, 1);
    v += __shfl_xor(v, 2);
    v += __shfl_xor(v, 4);
    v += __shfl_xor(v, 8);
    if (c == 0) {
      int row = row0 + wid * 64 + (k >> 2) * 16 + g * 4 + (k & 3);
      atomicAdd(&row_sum[row], v);
    }
  }
}

__global__ __launch_bounds__(256) void finalize_kernel(
    const float* __restrict__ row_sum, const float* __restrict__ pos,
    float* __restrict__ out, int n) {
  int t = threadIdx.x;
  float s = 0.f;
  #pragma unroll 4
  for (int i = t; i < n; i += 256) s += __logf(row_sum[i]) - pos[i];
  #pragma unroll
  for (int m = 1; m < 64; m <<= 1) s += __shfl_xor(s, m);
  __shared__ float red[4];
  if ((t & 63) == 0) red[t >> 6] = s;
  __syncthreads();
  if (t == 0) out[0] = red[0] + red[1] + red[2] + red[3];  // -loss = sum(lse - pos)
}

extern "C" void kernel_launch(void* const* d_in, const int* in_sizes, int n_in,
                              void* d_out, int out_size, void* d_ws, size_t ws_size,
                              hipStream_t stream) {
  const float* q = (const float*)d_in[0];
  const float* r = (const float*)d_in[1];
  int n = in_sizes[0] / DDIM;  // 8192

  char* w = (char*)d_ws;
  size_t f8Bytes = (size_t)n * DDIM;
  unsigned char* qf8 = (unsigned char*)w;
  unsigned char* rf8 = (unsigned char*)(w + f8Bytes);
  float* pos     = (float*)(w + 2 * f8Bytes);
  float* row_sum = pos + n;

  prep_kernel<<<n / 4, 256, 0, stream>>>(q, r, qf8, rf8, pos, row_sum);

  dim3 grid(n / BROWS, n / (NTILES * BCOLS));   // 32 x 32 = 1024 blocks (4/CU)
  gemm_lse_kernel<<<grid, 256, 0, stream>>>(qf8, rf8, row_sum);

  finalize_kernel<<<1, 256, 0, stream>>>(row_sum, pos, (float*)d_out, n);
}

// Round 11
// 51.742 us; speedup vs baseline: 1.4631x; 1.4631x over previous
//
#include <hip/hip_runtime.h>
#include <hip/hip_bf16.h>

#define DDIM   256   // K (feature dim)
#define BROWS  256   // block output rows (4 waves x 64 rows)
#define BCOLS   32   // B tile columns
#define NTILES   8   // B tiles per block -> 256 cols per chunk

typedef float f32x4 __attribute__((ext_vector_type(4)));

// pack 4 f32 -> 4 fp8 e4m3 bytes
__device__ __forceinline__ unsigned int pack4_fp8(float a0, float a1, float a2, float a3) {
  int v = __builtin_amdgcn_cvt_pk_fp8_f32(a0, a1, 0, false);   // bytes 0,1
  v = __builtin_amdgcn_cvt_pk_fp8_f32(a2, a3, v, true);        // bytes 2,3
  return (unsigned int)v;
}

// ---- prep: one wave per row; writes UNIT-NORM fp8 rows + exact f32 diag ----
__global__ __launch_bounds__(256) void prep_kernel(
    const float* __restrict__ q, const float* __restrict__ r,
    unsigned char* __restrict__ qf8, unsigned char* __restrict__ rf8,
    float* __restrict__ pos, float* __restrict__ row_sum) {
  int lane = threadIdx.x & 63, wave = threadIdx.x >> 6;
  int row = blockIdx.x * 4 + wave;
  size_t base = (size_t)row * DDIM + lane * 4;
  float4 qv = *(const float4*)(q + base);
  float4 rv = *(const float4*)(r + base);
  float qq = qv.x*qv.x + qv.y*qv.y + qv.z*qv.z + qv.w*qv.w;
  float rr = rv.x*rv.x + rv.y*rv.y + rv.z*rv.z + rv.w*rv.w;
  float qr = qv.x*rv.x + qv.y*rv.y + qv.z*rv.z + qv.w*rv.w;
  #pragma unroll
  for (int m = 1; m < 64; m <<= 1) {
    qq += __shfl_xor(qq, m);
    rr += __shfl_xor(rr, m);
    qr += __shfl_xor(qr, m);
  }
  float iq = 1.0f / sqrtf(qq);
  float ir = 1.0f / sqrtf(rr);
  unsigned int qp = pack4_fp8(qv.x*iq, qv.y*iq, qv.z*iq, qv.w*iq);
  unsigned int rp = pack4_fp8(rv.x*ir, rv.y*ir, rv.z*ir, rv.w*ir);
  *(unsigned int*)(qf8 + base) = qp;
  *(unsigned int*)(rf8 + base) = rp;
  if (lane == 0) {
    pos[row] = qr * iq * ir;   // exact f32 diagonal from raw inputs
    row_sum[row] = 0.0f;
  }
}

// stage one 32-col x 256-K fp8 B tile (8 KB) into LDS, async.
// LDS layout: byte(col, koff) = col*256 + (koff ^ ((col&15)<<4)).
// global_load_lds writes linearly (uniform base + lane*16), so the SOURCE is
// inverse-swizzled (rule 21). 256 threads x 2 iters x 16B = 8 KB.
__device__ __forceinline__ void stage_tile(unsigned char* dst,
                                           const unsigned char* src_base,
                                           int col0, int wid, int lane) {
  const char* gb = (const char*)src_base + (size_t)col0 * 256;
  #pragma unroll
  for (int it = 0; it < 2; ++it) {
    int cb = it * 256 + wid * 64;        // wave-uniform chunk base (16B units)
    int ch = cb + lane;                  // 0..511
    int cc = ch >> 4;                    // tile-local col 0..31
    int w  = (ch & 15) << 4;             // 16B block within the 256B row
    int src = cc * 256 + (w ^ ((cc & 15) << 4));
    __builtin_amdgcn_global_load_lds(
        (const __attribute__((address_space(1))) void*)(gb + src),
        (__attribute__((address_space(3))) void*)(dst + cb * 16),
        16, 0, 0);
  }
}

// one 256x32 tile: wave = 64 rows x 32 cols. A (fp8) resident in registers
// (4 frags x 8 K-slices = 64 VGPR), B from LDS b64. Per K-step:
// 2 ds_read_b64 -> 8 MFMA (3.2:1 MFMA:LDS at CU level).
__device__ __forceinline__ void compute_tile(
    const unsigned char* Bt, const long (&av)[4][8], float (&rs)[16],
    int g, int c) {
  // cols c and c+16 share swz = c<<4 (since (c+16)&15 == c); col c+16 is a
  // flat +4096B offset (imm-foldable into the second ds_read).
  const char* Bb = (const char*)Bt + (size_t)c * 256;
  f32x4 acc[4][2];
  const f32x4 zero = {0.f, 0.f, 0.f, 0.f};
  #pragma unroll
  for (int m = 0; m < 4; ++m) { acc[m][0] = zero; acc[m][1] = zero; }

  #pragma unroll
  for (int ks = 0; ks < 8; ++ks) {
    int koff = (ks * 32 + g * 8) ^ (c << 4);
    long bv0 = *(const long*)(Bb + koff);
    long bv1 = *(const long*)(Bb + 4096 + koff);
    #pragma unroll
    for (int m = 0; m < 4; ++m) {
      acc[m][0] = __builtin_amdgcn_mfma_f32_16x16x32_fp8_fp8(av[m][ks], bv0, acc[m][0], 0, 0, 0);
      acc[m][1] = __builtin_amdgcn_mfma_f32_16x16x32_fp8_fp8(av[m][ks], bv1, acc[m][1], 0, 0, 0);
    }
  }

  // unit-norm inputs: score = acc. C layout: col = half*16+c, row = m*16+g*4+jj
  #pragma unroll
  for (int m = 0; m < 4; ++m)
    #pragma unroll
    for (int jj = 0; jj < 4; ++jj)
      rs[m * 4 + jj] += __expf(acc[m][0][jj]) + __expf(acc[m][1][jj]);
}

// 256 threads = 4 waves x 64 rows. launch_bounds(256, 2): the empirical
// budget rule across R5-R10 is arch-VGPR cap = 512/(2*min_waves) — (x,4)
// gives 64 and SPILLS the accumulators (R8/R10: 50-85 MB scratch), (x,2)
// gives 128 arch + AGPR accum beyond it (R9: 88+64, zero spill). Demand
// here is ~100 arch + 32 acc ~ 132 total -> 3 waves/SIMD -> THREE 4-wave
// blocks resident per CU: three independent barrier groups, so one block's
// stage/drain hides under the other two blocks' MFMA phases (R9 had one
// 8-wave block: clean codegen but exposed barriers -> MfmaUtil 26%).
__global__ __launch_bounds__(256, 2) void gemm_lse_kernel(
    const unsigned char* __restrict__ qf8, const unsigned char* __restrict__ rf8,
    float* __restrict__ row_sum) {
  __shared__ __attribute__((aligned(16))) unsigned char Bl[2][BCOLS * DDIM]; // 2 x 8 KB

  const int tid  = threadIdx.x;
  const int lane = tid & 63;
  const int wid  = tid >> 6;            // 4 waves, each owns 64 rows
  const int g = lane >> 4, c = lane & 15;
  const int row0  = blockIdx.x * BROWS;
  const int col00 = blockIdx.y * (NTILES * BCOLS);

  // issue stage of tile 0 first; latency hides under the A-register loads
  stage_tile(&Bl[0][0], rf8, col00, wid, lane);

  // A fragments -> registers (4 row-frags x 8 K-slices = 64 VGPR), read once
  long av[4][8];
  const char* Ab = (const char*)qf8;
  #pragma unroll
  for (int m = 0; m < 4; ++m) {
    size_t rb = (size_t)(row0 + wid * 64 + m * 16 + c) * 256;
    #pragma unroll
    for (int ks = 0; ks < 8; ++ks)
      av[m][ks] = *(const long*)(Ab + rb + ks * 32 + g * 8);
  }

  float rs[16];
  #pragma unroll
  for (int k = 0; k < 16; ++k) rs[k] = 0.0f;

  __syncthreads();   // tile 0 resident

  // 2-phase pipeline: issue stage(t+1) BEFORE compute(t); the single
  // __syncthreads per tile drains vmcnt AFTER compute so in-flight loads
  // hide under MFMA. Manual x2 unroll keeps buffer indices compile-time.
  for (int t = 0; t < NTILES; t += 2) {
    if (t + 1 < NTILES)
      stage_tile(&Bl[1][0], rf8, col00 + (t + 1) * BCOLS, wid, lane);
    compute_tile(&Bl[0][0], av, rs, g, c);
    __syncthreads();

    if (t + 2 < NTILES)
      stage_tile(&Bl[0][0], rf8, col00 + (t + 2) * BCOLS, wid, lane);
    compute_tile(&Bl[1][0], av, rs, g, c);
    __syncthreads();
  }

  // reduce the 16 column-lanes holding the same row, one atomic per row
  #pragma unroll
  for (int k = 0; k < 16; ++k) {
    float v = rs[k];
    v += __shfl_xor(v, 1);
    v += __shfl_xor(v, 2);
    v += __shfl_xor(v, 4);
    v += __shfl_xor(v, 8);
    if (c == 0) {
      int row = row0 + wid * 64 + (k >> 2) * 16 + g * 4 + (k & 3);
      atomicAdd(&row_sum[row], v);
    }
  }
}

__global__ __launch_bounds__(256) void finalize_kernel(
    const float* __restrict__ row_sum, const float* __restrict__ pos,
    float* __restrict__ out, int n) {
  int t = threadIdx.x;
  float s = 0.f;
  #pragma unroll 4
  for (int i = t; i < n; i += 256) s += __logf(row_sum[i]) - pos[i];
  #pragma unroll
  for (int m = 1; m < 64; m <<= 1) s += __shfl_xor(s, m);
  __shared__ float red[4];
  if ((t & 63) == 0) red[t >> 6] = s;
  __syncthreads();
  if (t == 0) out[0] = red[0] + red[1] + red[2] + red[3];  // -loss = sum(lse - pos)
}

extern "C" void kernel_launch(void* const* d_in, const int* in_sizes, int n_in,
                              void* d_out, int out_size, void* d_ws, size_t ws_size,
                              hipStream_t stream) {
  const float* q = (const float*)d_in[0];
  const float* r = (const float*)d_in[1];
  int n = in_sizes[0] / DDIM;  // 8192

  char* w = (char*)d_ws;
  size_t f8Bytes = (size_t)n * DDIM;
  unsigned char* qf8 = (unsigned char*)w;
  unsigned char* rf8 = (unsigned char*)(w + f8Bytes);
  float* pos     = (float*)(w + 2 * f8Bytes);
  float* row_sum = pos + n;

  prep_kernel<<<n / 4, 256, 0, stream>>>(q, r, qf8, rf8, pos, row_sum);

  dim3 grid(n / BROWS, n / (NTILES * BCOLS));   // 32 x 32 = 1024 blocks
  gemm_lse_kernel<<<grid, 256, 0, stream>>>(qf8, rf8, row_sum);

  finalize_kernel<<<1, 256, 0, stream>>>(row_sum, pos, (float*)d_out, n);
}